// Round 1
// 183.565 us; speedup vs baseline: 1.0508x; 1.0508x over previous
//
#include <hip/hip_runtime.h>
#include <hip/hip_bf16.h>
#include <math.h>

// Problem constants: N=10000, E=160000, D=128, H=4, C=128, HC=512
#define D_DIM 128
#define HC_DIM 512
#define CAP 128  // per-node edge bucket capacity (deg ~ Poisson(16); P(deg>=128)<1e-60)
#define REP 4    // colsum/colsq replica slots (keeps per-address atomic depth at 2500/REP=625)

typedef __attribute__((ext_vector_type(8))) short bf16x8;
typedef __attribute__((ext_vector_type(4))) float f32x4;
typedef __attribute__((ext_vector_type(2))) float f32x2;
typedef __attribute__((ext_vector_type(2))) _Float16 h16x2;

static __device__ __forceinline__ unsigned short f2bf(float f) {
  unsigned u = __float_as_uint(f);
  unsigned r = (u + 0x7fffu + ((u >> 16) & 1u)) >> 16;  // RNE
  return (unsigned short)r;
}
static __device__ __forceinline__ float bflo(unsigned u) {
  return __uint_as_float(u << 16);
}
static __device__ __forceinline__ float bfhi(unsigned u) {
  return __uint_as_float(u & 0xffff0000u);
}

// ---------------------------------------------------------------------------
// prep: cast x -> bf16; build Wt [1664][128] bf16 (coalesced source reads);
// bcat[1664]; zero counter region (cnt|colsum|colsq).
// ---------------------------------------------------------------------------
__global__ void prep_kernel(const float* __restrict__ x,
                            const float* __restrict__ Wq, const float* __restrict__ Wk,
                            const float* __restrict__ Wv, const float* __restrict__ Wskip,
                            const float* __restrict__ bq, const float* __restrict__ bk,
                            const float* __restrict__ bv, const float* __restrict__ bskip,
                            unsigned short* __restrict__ xb,
                            unsigned short* __restrict__ wcat,
                            float* __restrict__ bcat,
                            int* __restrict__ zbase, int zwords, int N) {
  int t = blockIdx.x * 256 + threadIdx.x;
  int X4 = N * 32;  // x float4 count
  if (t < X4) {
    float4 f = *(const float4*)&x[t * 4];
    ushort4 o;
    o.x = f2bf(f.x); o.y = f2bf(f.y); o.z = f2bf(f.z); o.w = f2bf(f.w);
    *(ushort4*)&xb[t * 4] = o;
  } else if (t < X4 + 1664 * 128) {
    int widx = t - X4;
    if (widx < 3 * 65536) {
      int segi = widx >> 16;       // 0=q 1=k 2=v
      int r = widx & 65535;
      int kk = r >> 9;             // 0..127
      int m = r & 511;             // consecutive -> coalesced source read
      const float* W = (segi == 0) ? Wq : (segi == 1) ? Wk : Wv;
      wcat[(size_t)(segi * 512 + m) * 128 + kk] = f2bf(W[kk * 512 + m]);
    } else {
      int r = widx - 3 * 65536;    // < 16384
      int kk = r >> 7;
      int m = r & 127;
      wcat[(size_t)(1536 + m) * 128 + kk] = f2bf(Wskip[kk * 128 + m]);
    }
  } else if (t < X4 + 1664 * 128 + 1664) {
    int b = t - X4 - 1664 * 128;
    bcat[b] = (b < 512) ? bq[b] : (b < 1024) ? bk[b - 512]
            : (b < 1536) ? bv[b - 1024] : bskip[b - 1536];
  } else if (t < X4 + 1664 * 128 + 1664 + zwords) {
    zbase[t - X4 - 1664 * 128 - 1664] = 0;
  }
}

// ---------------------------------------------------------------------------
// LDS-free MFMA GEMM + slotted edge scatter (no hist/scan needed).
// Safe fusion: no barriers in this kernel -> scatter atomics never gate
// a barrier drain.
// [N x 1664] = Xb[N x 128] @ Wt[1664 x 128]^T + bcat.
// cols 0-511 -> q bf16; 512-1023 -> k f16; 1024-1535 -> v fp8;
// 1536-1663 -> skip fp32.
// ---------------------------------------------------------------------------
__global__ __launch_bounds__(256) void gemm_mfma_kernel(
    const unsigned short* __restrict__ Xb, const unsigned short* __restrict__ Wt,
    const float* __restrict__ bcat, unsigned short* __restrict__ qb,
    unsigned short* __restrict__ kf, unsigned char* __restrict__ v8,
    float* __restrict__ skip,
    const int* __restrict__ src, const int* __restrict__ dst,
    int* __restrict__ cnt, int* __restrict__ bsrc, int N, int E) {
  const int tid = threadIdx.x;
  // --- slotted scatter slice (no barriers anywhere in this kernel) ---
  {
    int nblk = gridDim.x * gridDim.y;
    int lb = blockIdx.y * gridDim.x + blockIdx.x;
    int per = (E + nblk - 1) / nblk;
    int e0 = lb * per;
    int e1 = min(e0 + per, E);
    for (int e = e0 + tid; e < e1; e += 256) {
      int d = dst[e];
      int p = atomicAdd(&cnt[d], 1);
      if (p < CAP) bsrc[d * CAP + p] = src[e];
    }
  }
  // --- GEMM ---
  const int wave = tid >> 6, lane = tid & 63;
  const int l16 = lane & 15, quad = lane >> 4;
  const int row0 = (blockIdx.x * 4 + wave) * 64;  // wave's 64-row slab
  const int col0 = blockIdx.y * 64;               // wave's 64-col slab

  const unsigned short* xrow[4];
#pragma unroll
  for (int i = 0; i < 4; ++i) {
    int r = row0 + i * 16 + l16;
    if (r >= N) r = N - 1;  // clamp; stores masked later
    xrow[i] = Xb + (size_t)r * 128;
  }
  const unsigned short* wrow[4];
  float bias[4];
#pragma unroll
  for (int j = 0; j < 4; ++j) {
    int c = col0 + j * 16 + l16;
    wrow[j] = Wt + (size_t)c * 128;
    bias[j] = bcat[c];
  }

  f32x4 acc[4][4] = {};
#pragma unroll
  for (int kk = 0; kk < 4; ++kk) {
    int k0 = kk * 32 + quad * 8;
    bf16x8 a[4], b[4];
#pragma unroll
    for (int i = 0; i < 4; ++i) a[i] = *(const bf16x8*)(xrow[i] + k0);
#pragma unroll
    for (int j = 0; j < 4; ++j) b[j] = *(const bf16x8*)(wrow[j] + k0);
#pragma unroll
    for (int i = 0; i < 4; ++i)
#pragma unroll
      for (int j = 0; j < 4; ++j)
        acc[i][j] = __builtin_amdgcn_mfma_f32_16x16x32_bf16(a[i], b[j], acc[i][j], 0, 0, 0);
  }

  // wave-uniform output kind: 0=q bf16, 1=k f16, 2=v fp8, 3=skip fp32
  const int kind = (col0 < 512) ? 0 : (col0 < 1024) ? 1 : (col0 < 1536) ? 2 : 3;
#pragma unroll
  for (int i = 0; i < 4; ++i) {
#pragma unroll
    for (int reg = 0; reg < 4; ++reg) {
      int r = row0 + i * 16 + quad * 4 + reg;
      if (r < N) {
#pragma unroll
        for (int j = 0; j < 4; ++j) {
          int cidx = col0 + j * 16 + l16;
          float val = acc[i][j][reg] + bias[j];
          if (kind == 0) {
            qb[(size_t)r * 512 + cidx] = f2bf(val);
          } else if (kind == 1) {
            _Float16 hv = (_Float16)val;
            kf[(size_t)r * 512 + cidx - 512] = *(unsigned short*)&hv;
          } else if (kind == 2) {
            int pk = __builtin_amdgcn_cvt_pk_fp8_f32(val, val, 0, false);
            v8[(size_t)r * 512 + cidx - 1024] = (unsigned char)pk;
          } else {
            skip[(size_t)r * 128 + cidx - 1536] = val;
          }
        }
      }
    }
  }
}

// ---------------------------------------------------------------------------
// Fused attention + combine.
// Block = 4 nodes (wave = node); per wave, head loop 0..3 so the wave ends
// holding all 4 heads' normalized outputs in registers -> beta gate, out2
// write and column moments happen in-block. Eliminates the oh buffer
// (10 MB write + 10 MB read) and the separate combine kernel.
// Edge list staged in LDS once per wave: removes the bsrc global load from
// the dependent gather chain in all 4 head passes.
// Moments: LDS reduce over the block's 4 nodes -> one atomic set per block
// into REP=4 replica slots (per-address depth 2500/4 = 625, same as the
// previously proven combine kernel).
// ---------------------------------------------------------------------------
__global__ __launch_bounds__(256) void attn_combine_kernel(
    const unsigned short* __restrict__ qb, const unsigned short* __restrict__ kf,
    const unsigned char* __restrict__ v8, const int* __restrict__ cnt,
    const int* __restrict__ bsrc, const float* __restrict__ skip,
    const float* __restrict__ Wbeta, float* __restrict__ out2,
    float* __restrict__ colsum, float* __restrict__ colsq, int N) {
  __shared__ int eL[4][CAP];        // per-wave edge list (wave-local, no sync needed)
  __shared__ float redS[4][128];
  __shared__ float redQ[4][128];
  int tid = threadIdx.x;
  int w = tid >> 6, lane = tid & 63;
  int node = blockIdx.x * 4 + w;
  bool nv = node < N;
  int nc = nv ? node : (N - 1);     // clamped for addressing; contributions masked
  int g = lane >> 4, j = lane & 15;

  int count = nv ? min(cnt[nc], CAP) : 0;
  const int* bp = bsrc + (size_t)nc * CAP;
  for (int i = lane; i < count; i += 64) eL[w][i] = bp[i];

  const float qscale = 0.08838834764831845f * 1.4426950408889634f;  // /sqrt(128)*log2e
  float am0 = 0.f, am1 = 0.f, am2 = 0.f, am3 = 0.f;
  float am4 = 0.f, am5 = 0.f, am6 = 0.f, am7 = 0.f;

#pragma unroll 1
  for (int h = 0; h < 4; ++h) {
    int4 qi = *(const int4*)(qb + (size_t)nc * 512 + h * 128 + j * 8);
    h16x2 qh0, qh1, qh2, qh3;
    qh0[0] = (_Float16)(bflo(qi.x) * qscale); qh0[1] = (_Float16)(bfhi(qi.x) * qscale);
    qh1[0] = (_Float16)(bflo(qi.y) * qscale); qh1[1] = (_Float16)(bfhi(qi.y) * qscale);
    qh2[0] = (_Float16)(bflo(qi.z) * qscale); qh2[1] = (_Float16)(bfhi(qi.z) * qscale);
    qh3[0] = (_Float16)(bflo(qi.w) * qscale); qh3[1] = (_Float16)(bfhi(qi.w) * qscale);

    const unsigned short* kb = kf + h * 128 + j * 8;
    const unsigned char* vb = v8 + h * 128 + j * 8;
    float lsum = 0.f;
    float o0 = 0.f, o1 = 0.f, o2 = 0.f, o3 = 0.f;
    float o4 = 0.f, o5 = 0.f, o6 = 0.f, o7 = 0.f;

    if (count > 0) {
      // prologue prefetch (e from LDS — cheap; k/v gather prefetched 1 iter ahead)
      int e = eL[w][(g < count) ? g : 0];
      uint4 kw = *(const uint4*)(kb + (size_t)e * 512);
      uint2 vw = *(const uint2*)(vb + (size_t)e * 512);
      for (int idx = 0; idx < count; idx += 4) {
        int rem = count - idx;
        int nrem = rem - 4;
        int en = (nrem > 0) ? eL[w][idx + 4 + ((g < nrem) ? g : 0)] : e;
        uint4 kwn = *(const uint4*)(kb + (size_t)en * 512);
        uint2 vwn = *(const uint2*)(vb + (size_t)en * 512);
        // compute with current kw/vw
        float p = __builtin_amdgcn_fdot2(qh0, *(h16x2*)&kw.x, 0.f, false);
        p = __builtin_amdgcn_fdot2(qh1, *(h16x2*)&kw.y, p, false);
        p = __builtin_amdgcn_fdot2(qh2, *(h16x2*)&kw.z, p, false);
        p = __builtin_amdgcn_fdot2(qh3, *(h16x2*)&kw.w, p, false);
        p += __shfl_xor(p, 1);
        p += __shfl_xor(p, 2);
        p += __shfl_xor(p, 4);
        p += __shfl_xor(p, 8);
        float a = (g < rem) ? p : -1e30f;
        float wgt = exp2f(a);  // exp2(-1e30) = 0 for inactive slots
        f32x2 v01 = __builtin_amdgcn_cvt_pk_f32_fp8(vw.x, false);
        f32x2 v23 = __builtin_amdgcn_cvt_pk_f32_fp8(vw.x, true);
        f32x2 v45 = __builtin_amdgcn_cvt_pk_f32_fp8(vw.y, false);
        f32x2 v67 = __builtin_amdgcn_cvt_pk_f32_fp8(vw.y, true);
        lsum += wgt;
        o0 += wgt * v01.x; o1 += wgt * v01.y;
        o2 += wgt * v23.x; o3 += wgt * v23.y;
        o4 += wgt * v45.x; o5 += wgt * v45.y;
        o6 += wgt * v67.x; o7 += wgt * v67.y;
        // rotate
        kw = kwn; vw = vwn; e = en;
      }
    }
    // cross-group butterfly (4 groups -> full sums on every lane)
    o0 += __shfl_xor(o0, 16); o0 += __shfl_xor(o0, 32);
    o1 += __shfl_xor(o1, 16); o1 += __shfl_xor(o1, 32);
    o2 += __shfl_xor(o2, 16); o2 += __shfl_xor(o2, 32);
    o3 += __shfl_xor(o3, 16); o3 += __shfl_xor(o3, 32);
    o4 += __shfl_xor(o4, 16); o4 += __shfl_xor(o4, 32);
    o5 += __shfl_xor(o5, 16); o5 += __shfl_xor(o5, 32);
    o6 += __shfl_xor(o6, 16); o6 += __shfl_xor(o6, 32);
    o7 += __shfl_xor(o7, 16); o7 += __shfl_xor(o7, 32);
    lsum += __shfl_xor(lsum, 16); lsum += __shfl_xor(lsum, 32);
    float inv = 0.25f / (lsum + 1e-16f);   // fold head-mean 1/4 into normalization
    am0 += o0 * inv; am1 += o1 * inv; am2 += o2 * inv; am3 += o3 * inv;
    am4 += o4 * inv; am5 += o5 * inv; am6 += o6 * inv; am7 += o7 * inv;
  }

  // --- beta gate (per-lane columns j*8..j*8+7, replicated across groups) ---
  float4 sl = *(const float4*)&skip[(size_t)nc * 128 + j * 8];
  float4 sh = *(const float4*)&skip[(size_t)nc * 128 + j * 8 + 4];
  float4 wal = *(const float4*)&Wbeta[j * 8];
  float4 wah = *(const float4*)&Wbeta[j * 8 + 4];
  float4 wbl = *(const float4*)&Wbeta[128 + j * 8];
  float4 wbh = *(const float4*)&Wbeta[128 + j * 8 + 4];
  float4 wcl = *(const float4*)&Wbeta[256 + j * 8];
  float4 wch = *(const float4*)&Wbeta[256 + j * 8 + 4];
  float p = am0 * wal.x + sl.x * wbl.x + (am0 - sl.x) * wcl.x
          + am1 * wal.y + sl.y * wbl.y + (am1 - sl.y) * wcl.y
          + am2 * wal.z + sl.z * wbl.z + (am2 - sl.z) * wcl.z
          + am3 * wal.w + sl.w * wbl.w + (am3 - sl.w) * wcl.w
          + am4 * wah.x + sh.x * wbh.x + (am4 - sh.x) * wch.x
          + am5 * wah.y + sh.y * wbh.y + (am5 - sh.y) * wch.y
          + am6 * wah.z + sh.z * wbh.z + (am6 - sh.z) * wch.z
          + am7 * wah.w + sh.w * wbh.w + (am7 - sh.w) * wch.w;
  // reduce over 16 j-lanes (each group holds all 128 cols -> full 384-dot)
  p += __shfl_xor(p, 1); p += __shfl_xor(p, 2);
  p += __shfl_xor(p, 4); p += __shfl_xor(p, 8);
  float beta = 1.f / (1.f + __expf(-p));
  float ob = 1.f - beta;
  float vm = nv ? 1.f : 0.f;
  float oc0 = (beta * sl.x + ob * am0) * vm;
  float oc1 = (beta * sl.y + ob * am1) * vm;
  float oc2 = (beta * sl.z + ob * am2) * vm;
  float oc3 = (beta * sl.w + ob * am3) * vm;
  float oc4 = (beta * sh.x + ob * am4) * vm;
  float oc5 = (beta * sh.y + ob * am5) * vm;
  float oc6 = (beta * sh.z + ob * am6) * vm;
  float oc7 = (beta * sh.w + ob * am7) * vm;

  if (g == 0) {
    float4 lo; lo.x = oc0; lo.y = oc1; lo.z = oc2; lo.w = oc3;
    float4 hi; hi.x = oc4; hi.y = oc5; hi.z = oc6; hi.w = oc7;
    if (nv) {
      *(float4*)&out2[(size_t)node * 128 + j * 8] = lo;
      *(float4*)&out2[(size_t)node * 128 + j * 8 + 4] = hi;
    }
    *(float4*)&redS[w][j * 8] = lo;
    *(float4*)&redS[w][j * 8 + 4] = hi;
    float4 ql; ql.x = oc0 * oc0; ql.y = oc1 * oc1; ql.z = oc2 * oc2; ql.w = oc3 * oc3;
    float4 qh; qh.x = oc4 * oc4; qh.y = oc5 * oc5; qh.z = oc6 * oc6; qh.w = oc7 * oc7;
    *(float4*)&redQ[w][j * 8] = ql;
    *(float4*)&redQ[w][j * 8 + 4] = qh;
  }
  __syncthreads();
  if (w == 0) {
    int c = lane * 2;
    float s0 = redS[0][c] + redS[1][c] + redS[2][c] + redS[3][c];
    float s1 = redS[0][c + 1] + redS[1][c + 1] + redS[2][c + 1] + redS[3][c + 1];
    float q0 = redQ[0][c] + redQ[1][c] + redQ[2][c] + redQ[3][c];
    float q1 = redQ[0][c + 1] + redQ[1][c + 1] + redQ[2][c + 1] + redQ[3][c + 1];
    int slot = (blockIdx.x & (REP - 1)) * 128;
    atomicAdd(&colsum[slot + c], s0);
    atomicAdd(&colsum[slot + c + 1], s1);
    atomicAdd(&colsq[slot + c], q0);
    atomicAdd(&colsq[slot + c + 1], q1);
  }
}

// ---------------------------------------------------------------------------
// finalize: sum REP replica column stats + groupnorm + exact GELU + residual
// ---------------------------------------------------------------------------
__global__ void final_kernel(const float* __restrict__ out2,
                             const float* __restrict__ colsum,
                             const float* __restrict__ colsq,
                             const float* __restrict__ gnw,
                             const float* __restrict__ gnb,
                             const float* __restrict__ gnms,
                             const float* __restrict__ x,
                             float* __restrict__ y, int total2, float invN) {
  int i = blockIdx.x * 256 + threadIdx.x;
  if (i < total2) {
    int c = (i & 63) * 2;
    float2 cs; cs.x = 0.f; cs.y = 0.f;
    float2 cq; cq.x = 0.f; cq.y = 0.f;
#pragma unroll
    for (int s = 0; s < REP; ++s) {
      float2 t = *(const float2*)&colsum[s * 128 + c];
      float2 u = *(const float2*)&colsq[s * 128 + c];
      cs.x += t.x; cs.y += t.y;
      cq.x += u.x; cq.y += u.y;
    }
    float2 gw = *(const float2*)&gnw[c];
    float2 gb = *(const float2*)&gnb[c];
    float2 gs = *(const float2*)&gnms[c];
    float mean0 = cs.x * invN, mean1 = cs.y * invN;
    float var0 = cq.x * invN - mean0 * mean0 * gs.x * (2.f - gs.x);
    float var1 = cq.y * invN - mean1 * mean1 * gs.y * (2.f - gs.y);
    float mul0 = gw.x / sqrtf(var0 + 1e-5f);
    float mul1 = gw.y / sqrtf(var1 + 1e-5f);
    float2 o = *(const float2*)&out2[i * 2];
    float2 xx = *(const float2*)&x[i * 2];
    float t0 = (o.x - gs.x * mean0) * mul0 + gb.x;
    float t1 = (o.y - gs.y * mean1) * mul1 + gb.y;
    float g0 = 0.5f * t0 * (1.f + erff(t0 * 0.70710678118654752f));
    float g1 = 0.5f * t1 * (1.f + erff(t1 * 0.70710678118654752f));
    float2 r; r.x = g0 + xx.x; r.y = g1 + xx.y;
    *(float2*)&y[i * 2] = r;
  }
}

extern "C" void kernel_launch(void* const* d_in, const int* in_sizes, int n_in,
                              void* d_out, int out_size, void* d_ws, size_t ws_size,
                              hipStream_t stream) {
  const float* x     = (const float*)d_in[0];
  const int*   ei    = (const int*)d_in[1];
  const float* Wq    = (const float*)d_in[2];
  const float* bq    = (const float*)d_in[3];
  const float* Wk    = (const float*)d_in[4];
  const float* bk    = (const float*)d_in[5];
  const float* Wv    = (const float*)d_in[6];
  const float* bv    = (const float*)d_in[7];
  const float* Wskip = (const float*)d_in[8];
  const float* bskip = (const float*)d_in[9];
  const float* Wbeta = (const float*)d_in[10];
  const float* gnw   = (const float*)d_in[11];
  const float* gnb   = (const float*)d_in[12];
  const float* gnms  = (const float*)d_in[13];

  const int N = in_sizes[0] / D_DIM;   // 10000
  const int E = in_sizes[1] / 2;       // 160000
  const int* src = ei;
  const int* dst = ei + E;

  // workspace carve-up (alias: xb over out2 — disjoint lifetimes:
  // xb dead after gemm; out2 first written in attn_combine)
  char* p = (char*)d_ws;
  unsigned short* qb = (unsigned short*)p; p += (size_t)N * 512 * 2;      // q bf16
  unsigned short* kf = (unsigned short*)p; p += (size_t)N * 512 * 2;      // k f16
  unsigned char*  v8 = (unsigned char*)p;  p += (size_t)N * 512;          // v fp8
  float*          skip = (float*)p;        p += (size_t)N * 128 * 4;
  float*          out2 = (float*)p;        p += (size_t)N * 128 * 4;
  // contiguous zero region: cnt | colsum[REP][128] | colsq[REP][128]
  int*   cnt    = (int*)p;   p += (size_t)N * 4;
  float* colsum = (float*)p; p += REP * 128 * 4;
  float* colsq  = (float*)p; p += REP * 128 * 4;
  int zwords = N + 2 * REP * 128;
  int* bsrc   = (int*)p;   p += (size_t)N * CAP * 4;  // slotted buckets
  unsigned short* wcat = (unsigned short*)p; p += (size_t)1664 * 128 * 2;
  float* bcat = (float*)p; p += 1664 * 4;
  unsigned short* xb = (unsigned short*)out2;  // alias

  // 1) prep (casts + weight transpose + zeroing)
  int prepTotal = N * 32 + 1664 * 128 + 1664 + zwords;
  prep_kernel<<<(prepTotal + 255) / 256, 256, 0, stream>>>(
      x, Wq, Wk, Wv, Wskip, bq, bk, bv, bskip, xb, wcat, bcat, cnt, zwords, N);

  // 2) LDS-free QKV+skip GEMM + slotted edge scatter (no barriers in kernel)
  gemm_mfma_kernel<<<dim3(40, 26), 256, 0, stream>>>(
      xb, wcat, bcat, qb, kf, v8, skip, src, dst, cnt, bsrc, N, E);

  // 3) fused attention (4 heads per wave) + beta gate + column moments
  attn_combine_kernel<<<(N + 3) / 4, 256, 0, stream>>>(
      qb, kf, v8, cnt, bsrc, skip, Wbeta, out2, colsum, colsq, N);

  // 4) finalize
  int total2 = N * D_DIM / 2;
  final_kernel<<<(total2 + 255) / 256, 256, 0, stream>>>(
      out2, colsum, colsq, gnw, gnb, gnms, x, (float*)d_out, total2, 1.f / (float)N);
}

// Round 2
// 178.902 us; speedup vs baseline: 1.0782x; 1.0261x over previous
//
#include <hip/hip_runtime.h>
#include <hip/hip_bf16.h>
#include <math.h>

// Problem constants: N=10000, E=160000, D=128, H=4, C=128, HC=512
#define D_DIM 128
#define HC_DIM 512
#define CAP 128  // per-node edge bucket capacity (deg ~ Poisson(16); P(deg>=128)<1e-60)
#define REP 4    // colsum/colsq replica slots (keeps per-address atomic depth at 2500/REP=625)

typedef __attribute__((ext_vector_type(8))) short bf16x8;
typedef __attribute__((ext_vector_type(4))) float f32x4;
typedef __attribute__((ext_vector_type(2))) float f32x2;
typedef __attribute__((ext_vector_type(2))) _Float16 h16x2;

static __device__ __forceinline__ unsigned short f2bf(float f) {
  unsigned u = __float_as_uint(f);
  unsigned r = (u + 0x7fffu + ((u >> 16) & 1u)) >> 16;  // RNE
  return (unsigned short)r;
}
static __device__ __forceinline__ float bflo(unsigned u) {
  return __uint_as_float(u << 16);
}
static __device__ __forceinline__ float bfhi(unsigned u) {
  return __uint_as_float(u & 0xffff0000u);
}

// ---------------------------------------------------------------------------
// prep: cast x -> bf16; build Wt [1664][128] bf16 (coalesced source reads);
// bcat[1664]; zero counter region (cnt|colsum|colsq).
// ---------------------------------------------------------------------------
__global__ void prep_kernel(const float* __restrict__ x,
                            const float* __restrict__ Wq, const float* __restrict__ Wk,
                            const float* __restrict__ Wv, const float* __restrict__ Wskip,
                            const float* __restrict__ bq, const float* __restrict__ bk,
                            const float* __restrict__ bv, const float* __restrict__ bskip,
                            unsigned short* __restrict__ xb,
                            unsigned short* __restrict__ wcat,
                            float* __restrict__ bcat,
                            int* __restrict__ zbase, int zwords, int N) {
  int t = blockIdx.x * 256 + threadIdx.x;
  int X4 = N * 32;  // x float4 count
  if (t < X4) {
    float4 f = *(const float4*)&x[t * 4];
    ushort4 o;
    o.x = f2bf(f.x); o.y = f2bf(f.y); o.z = f2bf(f.z); o.w = f2bf(f.w);
    *(ushort4*)&xb[t * 4] = o;
  } else if (t < X4 + 1664 * 128) {
    int widx = t - X4;
    if (widx < 3 * 65536) {
      int segi = widx >> 16;       // 0=q 1=k 2=v
      int r = widx & 65535;
      int kk = r >> 9;             // 0..127
      int m = r & 511;             // consecutive -> coalesced source read
      const float* W = (segi == 0) ? Wq : (segi == 1) ? Wk : Wv;
      wcat[(size_t)(segi * 512 + m) * 128 + kk] = f2bf(W[kk * 512 + m]);
    } else {
      int r = widx - 3 * 65536;    // < 16384
      int kk = r >> 7;
      int m = r & 127;
      wcat[(size_t)(1536 + m) * 128 + kk] = f2bf(Wskip[kk * 128 + m]);
    }
  } else if (t < X4 + 1664 * 128 + 1664) {
    int b = t - X4 - 1664 * 128;
    bcat[b] = (b < 512) ? bq[b] : (b < 1024) ? bk[b - 512]
            : (b < 1536) ? bv[b - 1024] : bskip[b - 1536];
  } else if (t < X4 + 1664 * 128 + 1664 + zwords) {
    zbase[t - X4 - 1664 * 128 - 1664] = 0;
  }
}

// ---------------------------------------------------------------------------
// LDS-free MFMA GEMM + slotted edge scatter (no hist/scan needed).
// Safe fusion: no barriers in this kernel -> scatter atomics never gate
// a barrier drain.
// [N x 1664] = Xb[N x 128] @ Wt[1664 x 128]^T + bcat.
// cols 0-511 -> q bf16; 512-1023 -> k f16; 1024-1535 -> v fp8;
// 1536-1663 -> skip fp32.
// ---------------------------------------------------------------------------
__global__ __launch_bounds__(256) void gemm_mfma_kernel(
    const unsigned short* __restrict__ Xb, const unsigned short* __restrict__ Wt,
    const float* __restrict__ bcat, unsigned short* __restrict__ qb,
    unsigned short* __restrict__ kf, unsigned char* __restrict__ v8,
    float* __restrict__ skip,
    const int* __restrict__ src, const int* __restrict__ dst,
    int* __restrict__ cnt, int* __restrict__ bsrc, int N, int E) {
  const int tid = threadIdx.x;
  // --- slotted scatter slice (no barriers anywhere in this kernel) ---
  {
    int nblk = gridDim.x * gridDim.y;
    int lb = blockIdx.y * gridDim.x + blockIdx.x;
    int per = (E + nblk - 1) / nblk;
    int e0 = lb * per;
    int e1 = min(e0 + per, E);
    for (int e = e0 + tid; e < e1; e += 256) {
      int d = dst[e];
      int p = atomicAdd(&cnt[d], 1);
      if (p < CAP) bsrc[d * CAP + p] = src[e];
    }
  }
  // --- GEMM ---
  const int wave = tid >> 6, lane = tid & 63;
  const int l16 = lane & 15, quad = lane >> 4;
  const int row0 = (blockIdx.x * 4 + wave) * 64;  // wave's 64-row slab
  const int col0 = blockIdx.y * 64;               // wave's 64-col slab

  const unsigned short* xrow[4];
#pragma unroll
  for (int i = 0; i < 4; ++i) {
    int r = row0 + i * 16 + l16;
    if (r >= N) r = N - 1;  // clamp; stores masked later
    xrow[i] = Xb + (size_t)r * 128;
  }
  const unsigned short* wrow[4];
  float bias[4];
#pragma unroll
  for (int j = 0; j < 4; ++j) {
    int c = col0 + j * 16 + l16;
    wrow[j] = Wt + (size_t)c * 128;
    bias[j] = bcat[c];
  }

  f32x4 acc[4][4] = {};
#pragma unroll
  for (int kk = 0; kk < 4; ++kk) {
    int k0 = kk * 32 + quad * 8;
    bf16x8 a[4], b[4];
#pragma unroll
    for (int i = 0; i < 4; ++i) a[i] = *(const bf16x8*)(xrow[i] + k0);
#pragma unroll
    for (int j = 0; j < 4; ++j) b[j] = *(const bf16x8*)(wrow[j] + k0);
#pragma unroll
    for (int i = 0; i < 4; ++i)
#pragma unroll
      for (int j = 0; j < 4; ++j)
        acc[i][j] = __builtin_amdgcn_mfma_f32_16x16x32_bf16(a[i], b[j], acc[i][j], 0, 0, 0);
  }

  // wave-uniform output kind: 0=q bf16, 1=k f16, 2=v fp8, 3=skip fp32
  const int kind = (col0 < 512) ? 0 : (col0 < 1024) ? 1 : (col0 < 1536) ? 2 : 3;
#pragma unroll
  for (int i = 0; i < 4; ++i) {
#pragma unroll
    for (int reg = 0; reg < 4; ++reg) {
      int r = row0 + i * 16 + quad * 4 + reg;
      if (r < N) {
#pragma unroll
        for (int j = 0; j < 4; ++j) {
          int cidx = col0 + j * 16 + l16;
          float val = acc[i][j][reg] + bias[j];
          if (kind == 0) {
            qb[(size_t)r * 512 + cidx] = f2bf(val);
          } else if (kind == 1) {
            _Float16 hv = (_Float16)val;
            kf[(size_t)r * 512 + cidx - 512] = *(unsigned short*)&hv;
          } else if (kind == 2) {
            int pk = __builtin_amdgcn_cvt_pk_fp8_f32(val, val, 0, false);
            v8[(size_t)r * 512 + cidx - 1024] = (unsigned char)pk;
          } else {
            skip[(size_t)r * 128 + cidx - 1536] = val;
          }
        }
      }
    }
  }
}

// ---------------------------------------------------------------------------
// Fused attention + combine, ALL 4 HEADS IN ONE EDGE LOOP.
// Block = 4 nodes (wave = node). Each 16-lane group owns one edge slot and
// computes all 4 heads for that edge per iteration: 4x compute per iteration
// and 4x fewer serial iterations than the head-phased loop -> gather latency
// is covered by compute instead of exposed (prev: VALUBusy 29%, hbm 20%,
// 59 us = latency-bound).
// Edge list staged in LDS once per wave. Beta gate + out2 + column moments
// in-block as before (REP=4 replica atomic slots).
// ---------------------------------------------------------------------------
__global__ __launch_bounds__(256) void attn_combine_kernel(
    const unsigned short* __restrict__ qb, const unsigned short* __restrict__ kf,
    const unsigned char* __restrict__ v8, const int* __restrict__ cnt,
    const int* __restrict__ bsrc, const float* __restrict__ skip,
    const float* __restrict__ Wbeta, float* __restrict__ out2,
    float* __restrict__ colsum, float* __restrict__ colsq, int N) {
  __shared__ int eL[4][CAP];        // per-wave edge list (wave-local, no sync needed)
  __shared__ float redS[4][128];
  __shared__ float redQ[4][128];
  int tid = threadIdx.x;
  int w = tid >> 6, lane = tid & 63;
  int node = blockIdx.x * 4 + w;
  bool nv = node < N;
  int nc = nv ? node : (N - 1);     // clamped for addressing; contributions masked
  int g = lane >> 4, j = lane & 15;

  int count = nv ? min(cnt[nc], CAP) : 0;
  const int* bp = bsrc + (size_t)nc * CAP;
  for (int i = lane; i < count; i += 64) eL[w][i] = bp[i];

  const float qscale = 0.08838834764831845f * 1.4426950408889634f;  // /sqrt(128)*log2e
  // stage q for all 4 heads (lane j holds halves j*8..j*8+7 of each head slice)
  h16x2 qh[4][4];
#pragma unroll
  for (int h = 0; h < 4; ++h) {
    int4 qi = *(const int4*)(qb + (size_t)nc * 512 + h * 128 + j * 8);
    qh[h][0][0] = (_Float16)(bflo(qi.x) * qscale); qh[h][0][1] = (_Float16)(bfhi(qi.x) * qscale);
    qh[h][1][0] = (_Float16)(bflo(qi.y) * qscale); qh[h][1][1] = (_Float16)(bfhi(qi.y) * qscale);
    qh[h][2][0] = (_Float16)(bflo(qi.z) * qscale); qh[h][2][1] = (_Float16)(bfhi(qi.z) * qscale);
    qh[h][3][0] = (_Float16)(bflo(qi.w) * qscale); qh[h][3][1] = (_Float16)(bfhi(qi.w) * qscale);
  }

  float o[4][8];
  float lsum[4];
#pragma unroll
  for (int h = 0; h < 4; ++h) {
    lsum[h] = 0.f;
#pragma unroll
    for (int r = 0; r < 8; ++r) o[h][r] = 0.f;
  }

  if (count > 0) {
    // prologue prefetch (edge index from LDS; k/v for all 4 heads)
    int e = eL[w][(g < count) ? g : 0];
    uint4 kw[4]; uint2 vw[4];
    {
      const unsigned short* kbe = kf + (size_t)e * 512 + j * 8;
      const unsigned char* vbe = v8 + (size_t)e * 512 + j * 8;
#pragma unroll
      for (int h = 0; h < 4; ++h) {
        kw[h] = *(const uint4*)(kbe + h * 128);
        vw[h] = *(const uint2*)(vbe + h * 128);
      }
    }
    for (int idx = 0; idx < count; idx += 4) {
      int rem = count - idx;
      int nrem = rem - 4;
      int en = (nrem > 0) ? eL[w][idx + 4 + ((g < nrem) ? g : 0)] : e;
      uint4 kwn[4]; uint2 vwn[4];
      {
        const unsigned short* kbe = kf + (size_t)en * 512 + j * 8;
        const unsigned char* vbe = v8 + (size_t)en * 512 + j * 8;
#pragma unroll
        for (int h = 0; h < 4; ++h) {
          kwn[h] = *(const uint4*)(kbe + h * 128);
          vwn[h] = *(const uint2*)(vbe + h * 128);
        }
      }
      bool act = (g < rem);
#pragma unroll
      for (int h = 0; h < 4; ++h) {
        float p = __builtin_amdgcn_fdot2(qh[h][0], *(h16x2*)&kw[h].x, 0.f, false);
        p = __builtin_amdgcn_fdot2(qh[h][1], *(h16x2*)&kw[h].y, p, false);
        p = __builtin_amdgcn_fdot2(qh[h][2], *(h16x2*)&kw[h].z, p, false);
        p = __builtin_amdgcn_fdot2(qh[h][3], *(h16x2*)&kw[h].w, p, false);
        p += __shfl_xor(p, 1);
        p += __shfl_xor(p, 2);
        p += __shfl_xor(p, 4);
        p += __shfl_xor(p, 8);
        float a = act ? p : -1e30f;
        float wgt = exp2f(a);  // exp2(-1e30) = 0 for inactive slots
        f32x2 v01 = __builtin_amdgcn_cvt_pk_f32_fp8(vw[h].x, false);
        f32x2 v23 = __builtin_amdgcn_cvt_pk_f32_fp8(vw[h].x, true);
        f32x2 v45 = __builtin_amdgcn_cvt_pk_f32_fp8(vw[h].y, false);
        f32x2 v67 = __builtin_amdgcn_cvt_pk_f32_fp8(vw[h].y, true);
        lsum[h] += wgt;
        o[h][0] += wgt * v01.x; o[h][1] += wgt * v01.y;
        o[h][2] += wgt * v23.x; o[h][3] += wgt * v23.y;
        o[h][4] += wgt * v45.x; o[h][5] += wgt * v45.y;
        o[h][6] += wgt * v67.x; o[h][7] += wgt * v67.y;
        // rotate this head's buffers
        kw[h] = kwn[h]; vw[h] = vwn[h];
      }
      e = en;
    }
  }
  // per-head cross-group butterfly + normalize, merged head-mean accumulation
  float am[8];
#pragma unroll
  for (int r = 0; r < 8; ++r) am[r] = 0.f;
#pragma unroll
  for (int h = 0; h < 4; ++h) {
#pragma unroll
    for (int r = 0; r < 8; ++r) {
      o[h][r] += __shfl_xor(o[h][r], 16);
      o[h][r] += __shfl_xor(o[h][r], 32);
    }
    lsum[h] += __shfl_xor(lsum[h], 16);
    lsum[h] += __shfl_xor(lsum[h], 32);
    float inv = 0.25f / (lsum[h] + 1e-16f);   // fold head-mean 1/4 into normalization
#pragma unroll
    for (int r = 0; r < 8; ++r) am[r] += o[h][r] * inv;
  }

  // --- beta gate (per-lane columns j*8..j*8+7, replicated across groups) ---
  float4 sl = *(const float4*)&skip[(size_t)nc * 128 + j * 8];
  float4 sh = *(const float4*)&skip[(size_t)nc * 128 + j * 8 + 4];
  float4 wal = *(const float4*)&Wbeta[j * 8];
  float4 wah = *(const float4*)&Wbeta[j * 8 + 4];
  float4 wbl = *(const float4*)&Wbeta[128 + j * 8];
  float4 wbh = *(const float4*)&Wbeta[128 + j * 8 + 4];
  float4 wcl = *(const float4*)&Wbeta[256 + j * 8];
  float4 wch = *(const float4*)&Wbeta[256 + j * 8 + 4];
  float p = am[0] * wal.x + sl.x * wbl.x + (am[0] - sl.x) * wcl.x
          + am[1] * wal.y + sl.y * wbl.y + (am[1] - sl.y) * wcl.y
          + am[2] * wal.z + sl.z * wbl.z + (am[2] - sl.z) * wcl.z
          + am[3] * wal.w + sl.w * wbl.w + (am[3] - sl.w) * wcl.w
          + am[4] * wah.x + sh.x * wbh.x + (am[4] - sh.x) * wch.x
          + am[5] * wah.y + sh.y * wbh.y + (am[5] - sh.y) * wch.y
          + am[6] * wah.z + sh.z * wbh.z + (am[6] - sh.z) * wch.z
          + am[7] * wah.w + sh.w * wbh.w + (am[7] - sh.w) * wch.w;
  // reduce over 16 j-lanes (each group holds all 128 cols -> full 384-dot)
  p += __shfl_xor(p, 1); p += __shfl_xor(p, 2);
  p += __shfl_xor(p, 4); p += __shfl_xor(p, 8);
  float beta = 1.f / (1.f + __expf(-p));
  float ob = 1.f - beta;
  float vm = nv ? 1.f : 0.f;
  float oc0 = (beta * sl.x + ob * am[0]) * vm;
  float oc1 = (beta * sl.y + ob * am[1]) * vm;
  float oc2 = (beta * sl.z + ob * am[2]) * vm;
  float oc3 = (beta * sl.w + ob * am[3]) * vm;
  float oc4 = (beta * sh.x + ob * am[4]) * vm;
  float oc5 = (beta * sh.y + ob * am[5]) * vm;
  float oc6 = (beta * sh.z + ob * am[6]) * vm;
  float oc7 = (beta * sh.w + ob * am[7]) * vm;

  if (g == 0) {
    float4 lo; lo.x = oc0; lo.y = oc1; lo.z = oc2; lo.w = oc3;
    float4 hi; hi.x = oc4; hi.y = oc5; hi.z = oc6; hi.w = oc7;
    if (nv) {
      *(float4*)&out2[(size_t)node * 128 + j * 8] = lo;
      *(float4*)&out2[(size_t)node * 128 + j * 8 + 4] = hi;
    }
    *(float4*)&redS[w][j * 8] = lo;
    *(float4*)&redS[w][j * 8 + 4] = hi;
    float4 ql; ql.x = oc0 * oc0; ql.y = oc1 * oc1; ql.z = oc2 * oc2; ql.w = oc3 * oc3;
    float4 qh2; qh2.x = oc4 * oc4; qh2.y = oc5 * oc5; qh2.z = oc6 * oc6; qh2.w = oc7 * oc7;
    *(float4*)&redQ[w][j * 8] = ql;
    *(float4*)&redQ[w][j * 8 + 4] = qh2;
  }
  __syncthreads();
  if (w == 0) {
    int c = lane * 2;
    float s0 = redS[0][c] + redS[1][c] + redS[2][c] + redS[3][c];
    float s1 = redS[0][c + 1] + redS[1][c + 1] + redS[2][c + 1] + redS[3][c + 1];
    float q0 = redQ[0][c] + redQ[1][c] + redQ[2][c] + redQ[3][c];
    float q1 = redQ[0][c + 1] + redQ[1][c + 1] + redQ[2][c + 1] + redQ[3][c + 1];
    int slot = (blockIdx.x & (REP - 1)) * 128;
    atomicAdd(&colsum[slot + c], s0);
    atomicAdd(&colsum[slot + c + 1], s1);
    atomicAdd(&colsq[slot + c], q0);
    atomicAdd(&colsq[slot + c + 1], q1);
  }
}

// ---------------------------------------------------------------------------
// finalize: sum REP replica column stats + groupnorm + exact GELU + residual
// ---------------------------------------------------------------------------
__global__ void final_kernel(const float* __restrict__ out2,
                             const float* __restrict__ colsum,
                             const float* __restrict__ colsq,
                             const float* __restrict__ gnw,
                             const float* __restrict__ gnb,
                             const float* __restrict__ gnms,
                             const float* __restrict__ x,
                             float* __restrict__ y, int total2, float invN) {
  int i = blockIdx.x * 256 + threadIdx.x;
  if (i < total2) {
    int c = (i & 63) * 2;
    float2 cs; cs.x = 0.f; cs.y = 0.f;
    float2 cq; cq.x = 0.f; cq.y = 0.f;
#pragma unroll
    for (int s = 0; s < REP; ++s) {
      float2 t = *(const float2*)&colsum[s * 128 + c];
      float2 u = *(const float2*)&colsq[s * 128 + c];
      cs.x += t.x; cs.y += t.y;
      cq.x += u.x; cq.y += u.y;
    }
    float2 gw = *(const float2*)&gnw[c];
    float2 gb = *(const float2*)&gnb[c];
    float2 gs = *(const float2*)&gnms[c];
    float mean0 = cs.x * invN, mean1 = cs.y * invN;
    float var0 = cq.x * invN - mean0 * mean0 * gs.x * (2.f - gs.x);
    float var1 = cq.y * invN - mean1 * mean1 * gs.y * (2.f - gs.y);
    float mul0 = gw.x / sqrtf(var0 + 1e-5f);
    float mul1 = gw.y / sqrtf(var1 + 1e-5f);
    float2 o = *(const float2*)&out2[i * 2];
    float2 xx = *(const float2*)&x[i * 2];
    float t0 = (o.x - gs.x * mean0) * mul0 + gb.x;
    float t1 = (o.y - gs.y * mean1) * mul1 + gb.y;
    float g0 = 0.5f * t0 * (1.f + erff(t0 * 0.70710678118654752f));
    float g1 = 0.5f * t1 * (1.f + erff(t1 * 0.70710678118654752f));
    float2 r; r.x = g0 + xx.x; r.y = g1 + xx.y;
    *(float2*)&y[i * 2] = r;
  }
}

extern "C" void kernel_launch(void* const* d_in, const int* in_sizes, int n_in,
                              void* d_out, int out_size, void* d_ws, size_t ws_size,
                              hipStream_t stream) {
  const float* x     = (const float*)d_in[0];
  const int*   ei    = (const int*)d_in[1];
  const float* Wq    = (const float*)d_in[2];
  const float* bq    = (const float*)d_in[3];
  const float* Wk    = (const float*)d_in[4];
  const float* bk    = (const float*)d_in[5];
  const float* Wv    = (const float*)d_in[6];
  const float* bv    = (const float*)d_in[7];
  const float* Wskip = (const float*)d_in[8];
  const float* bskip = (const float*)d_in[9];
  const float* Wbeta = (const float*)d_in[10];
  const float* gnw   = (const float*)d_in[11];
  const float* gnb   = (const float*)d_in[12];
  const float* gnms  = (const float*)d_in[13];

  const int N = in_sizes[0] / D_DIM;   // 10000
  const int E = in_sizes[1] / 2;       // 160000
  const int* src = ei;
  const int* dst = ei + E;

  // workspace carve-up (alias: xb over out2 — disjoint lifetimes:
  // xb dead after gemm; out2 first written in attn_combine)
  char* p = (char*)d_ws;
  unsigned short* qb = (unsigned short*)p; p += (size_t)N * 512 * 2;      // q bf16
  unsigned short* kf = (unsigned short*)p; p += (size_t)N * 512 * 2;      // k f16
  unsigned char*  v8 = (unsigned char*)p;  p += (size_t)N * 512;          // v fp8
  float*          skip = (float*)p;        p += (size_t)N * 128 * 4;
  float*          out2 = (float*)p;        p += (size_t)N * 128 * 4;
  // contiguous zero region: cnt | colsum[REP][128] | colsq[REP][128]
  int*   cnt    = (int*)p;   p += (size_t)N * 4;
  float* colsum = (float*)p; p += REP * 128 * 4;
  float* colsq  = (float*)p; p += REP * 128 * 4;
  int zwords = N + 2 * REP * 128;
  int* bsrc   = (int*)p;   p += (size_t)N * CAP * 4;  // slotted buckets
  unsigned short* wcat = (unsigned short*)p; p += (size_t)1664 * 128 * 2;
  float* bcat = (float*)p; p += 1664 * 4;
  unsigned short* xb = (unsigned short*)out2;  // alias

  // 1) prep (casts + weight transpose + zeroing)
  int prepTotal = N * 32 + 1664 * 128 + 1664 + zwords;
  prep_kernel<<<(prepTotal + 255) / 256, 256, 0, stream>>>(
      x, Wq, Wk, Wv, Wskip, bq, bk, bv, bskip, xb, wcat, bcat, cnt, zwords, N);

  // 2) LDS-free QKV+skip GEMM + slotted edge scatter (no barriers in kernel)
  gemm_mfma_kernel<<<dim3(40, 26), 256, 0, stream>>>(
      xb, wcat, bcat, qb, kf, v8, skip, src, dst, cnt, bsrc, N, E);

  // 3) fused attention (all heads per edge) + beta gate + column moments
  attn_combine_kernel<<<(N + 3) / 4, 256, 0, stream>>>(
      qb, kf, v8, cnt, bsrc, skip, Wbeta, out2, colsum, colsq, N);

  // 4) finalize
  int total2 = N * D_DIM / 2;
  final_kernel<<<(total2 + 255) / 256, 256, 0, stream>>>(
      out2, colsum, colsq, gnw, gnb, gnms, x, (float*)d_out, total2, 1.f / (float)N);
}